// Round 6
// baseline (59.954 us; speedup 1.0000x reference)
//
#include <hip/hip_runtime.h>
#include <hip/hip_bf16.h>

#define NF 262144   // C*H*W
#define NROWS 32    // batch
#define BK 128      // tile cols (floats) staged per block-tile
#define SLICE 1120  // floats per slice: 1024 cross + 32 pos + 32 sq1 + 32 sq2
#define NSLICES 16

typedef __attribute__((ext_vector_type(8))) __bf16 bf16x8;
typedef __attribute__((ext_vector_type(16))) float f32x16;

__device__ __forceinline__ float sigmoid_fast(float x) {
    float e = __expf(-x);
    return __builtin_amdgcn_rcpf(1.0f + e);
}

__device__ __forceinline__ void gload16(const float* g, float* l) {
    __builtin_amdgcn_global_load_lds(
        (const __attribute__((address_space(1))) void*)g,
        (__attribute__((address_space(3))) void*)l, 16, 0, 0);
}

// LDS layout (floats): array a at a*4096; row r at +r*128.
// Staged so that LDS[a][row][chunk c] = G_a[row][c ^ (row&15)]  (16B chunks, XOR involution).
// Read of G[r][c] therefore uses LDS chunk (c ^ (r&15)).
__global__ __launch_bounds__(256, 3) void cl_main(const float* __restrict__ in1,
                                                  const float* __restrict__ in2,
                                                  const float* __restrict__ msk,
                                                  float* __restrict__ ws) {
    __shared__ float smem[12288];   // 48 KB, reused for epilogue

    const int tid  = threadIdx.x;
    const int w    = tid >> 6;     // wave 0..3
    const int lane = tid & 63;
    const int r    = lane & 31;    // MFMA fragment row this lane owns
    const int g    = lane >> 5;    // k-half within 16-col MFMA step
    const int jrow = lane >> 5;    // staging: which row of the pair
    const int jchk = lane & 31;    // staging: 16B chunk within 512B row-seg
    const int rsw  = r & 15;       // read-side swizzle key

    f32x16 acc;
    #pragma unroll
    for (int k = 0; k < 16; ++k) acc[k] = 0.0f;
    float pos = 0.0f, q1 = 0.0f, q2 = 0.0f;

    for (int t = 0; t < 2; ++t) {
        const int coloff = (blockIdx.x * 2 + t) * BK;

        // ---- stage tile: 48 x global_load_lds (1KB each), 12 per wave ----
        // Lane l of the wave writes LDS chunk l of the 1KB block (linear dest);
        // the XOR swizzle is applied on the per-lane GLOBAL source address.
        #pragma unroll
        for (int k = 0; k < 12; ++k) {
            const int n   = w * 12 + k;    // 0..47
            const int a   = n >> 4;        // array 0..2
            const int rp  = n & 15;        // row pair
            const int row = rp * 2 + jrow; // per-lane row (0..31)
            const float* gsrc = (a == 0) ? in1 : (a == 1) ? in2 : msk;
            gload16(gsrc + (size_t)row * NF + coloff + ((jchk ^ (row & 15)) << 2),
                    smem + a * 4096 + rp * 256);
        }
        __syncthreads();   // compiler drains vmcnt(0) before the barrier

        // ---- compute: wave w owns MFMA steps s = 2w, 2w+1 (cols w*32 .. w*32+31) ----
        #pragma unroll
        for (int sl = 0; sl < 2; ++sl) {
            const int s  = w * 2 + sl;
            const int c1 = s * 4 + g * 2;
            const float* base = smem + r * 128;
            float4 A0 = *(const float4*)(base +        ((c1       ^ rsw) << 2));
            float4 A1 = *(const float4*)(base +        (((c1 + 1) ^ rsw) << 2));
            float4 B0 = *(const float4*)(base + 4096 + ((c1       ^ rsw) << 2));
            float4 B1 = *(const float4*)(base + 4096 + (((c1 + 1) ^ rsw) << 2));
            float4 M0 = *(const float4*)(base + 8192 + ((c1       ^ rsw) << 2));
            float4 M1 = *(const float4*)(base + 8192 + (((c1 + 1) ^ rsw) << 2));

            float xa[8], xb[8], xm[8];
            *(float4*)&xa[0] = A0; *(float4*)&xa[4] = A1;
            *(float4*)&xb[0] = B0; *(float4*)&xb[4] = B1;
            *(float4*)&xm[0] = M0; *(float4*)&xm[4] = M1;

            bf16x8 fa, fb;
            #pragma unroll
            for (int e = 0; e < 8; ++e) {
                float sa = sigmoid_fast(xa[e]);
                float sb = sigmoid_fast(xb[e]);
                float d  = xm[e] * (sa - sb);
                pos = fmaf(d, d, pos);
                q1  = fmaf(sa, sa, q1);
                q2  = fmaf(sb, sb, q2);
                fa[e] = (__bf16)sa;
                fb[e] = (__bf16)sb;
            }
            acc = __builtin_amdgcn_mfma_f32_32x32x16_bf16(fa, fb, acc, 0, 0, 0);
        }
        __syncthreads();   // tile consumed; safe to overwrite LDS
    }

    // ---- block reduction in LDS (reuse smem) ----
    float* s_cross = smem;          // 1024 floats
    float* s_vec   = smem + 1024;   // 96 floats
    for (int idx = tid; idx < 1024; idx += 256) s_cross[idx] = 0.0f;
    if (tid < 96) s_vec[tid] = 0.0f;
    __syncthreads();

    pos += __shfl_down(pos, 32);
    q1  += __shfl_down(q1, 32);
    q2  += __shfl_down(q2, 32);
    if (lane < 32) {
        atomicAdd(&s_vec[r],      pos);
        atomicAdd(&s_vec[32 + r], q1);
        atomicAdd(&s_vec[64 + r], q2);
    }
    const int col = lane & 31;
    const int rhi = (lane >> 5) * 4;
    #pragma unroll
    for (int reg = 0; reg < 16; ++reg) {
        const int row = (reg & 3) + 8 * (reg >> 2) + rhi;  // verified C/D mapping
        atomicAdd(&s_cross[row * 32 + col], acc[reg]);
    }
    __syncthreads();

    // ---- sharded global accumulation ----
    float* slice = ws + (size_t)(blockIdx.x & (NSLICES - 1)) * SLICE;
    for (int idx = tid; idx < 1024; idx += 256) atomicAdd(&slice[idx], s_cross[idx]);
    if (tid < 96) atomicAdd(&slice[1024 + tid], s_vec[tid]);
}

__global__ __launch_bounds__(1024) void cl_final(const float* __restrict__ ws,
                                                 float* __restrict__ out) {
    __shared__ float s_loss[32];
    const int tid = threadIdx.x;
    const int i = tid >> 5, j = tid & 31;
    const float invN = 1.0f / (float)NF;

    float c = 0.0f, p = 0.0f, s1 = 0.0f, s2 = 0.0f;
    #pragma unroll
    for (int k = 0; k < NSLICES; ++k) {
        const float* sl = ws + (size_t)k * SLICE;
        c  += sl[i * 32 + j];
        p  += sl[1024 + i];
        s1 += sl[1056 + i];
        s2 += sl[1088 + j];
    }

    float d = (s1 + s2 - 2.0f * c) * invN;
    float sim = (i == j) ? 0.0f : expf(-d * 10.0f);   // TAU = 0.1
    #pragma unroll
    for (int off = 16; off; off >>= 1) sim += __shfl_xor(sim, off);

    if (j == 0) {
        float sp = expf(-p * invN * 10.0f);
        s_loss[i] = -logf(sp / (sp + sim));
    }
    __syncthreads();
    if (tid == 0) {
        float t = 0.0f;
        #pragma unroll
        for (int k = 0; k < 32; ++k) t += s_loss[k];
        out[0] = t * (1.0f / 32.0f);
    }
}

extern "C" void kernel_launch(void* const* d_in, const int* in_sizes, int n_in,
                              void* d_out, int out_size, void* d_ws, size_t ws_size,
                              hipStream_t stream) {
    const float* in1 = (const float*)d_in[0];
    const float* in2 = (const float*)d_in[1];
    const float* msk = (const float*)d_in[2];
    float* out = (float*)d_out;
    float* ws  = (float*)d_ws;

    hipMemsetAsync(ws, 0, NSLICES * SLICE * sizeof(float), stream);
    cl_main<<<1024, 256, 0, stream>>>(in1, in2, msk, ws);
    cl_final<<<1, 1024, 0, stream>>>(ws, out);
}

// Round 7
// 44.990 us; speedup vs baseline: 1.3326x; 1.3326x over previous
//
#include <hip/hip_runtime.h>
#include <hip/hip_bf16.h>

#define NF 262144   // C*H*W
#define NROWS 32    // batch
#define BK 64       // tile cols (floats) per stage
#define TPB 4       // tiles per block
#define SLICE 1120  // floats per slice: 1024 cross + 32 pos + 32 sq1 + 32 sq2
#define NSLICES 16

typedef __attribute__((ext_vector_type(8))) __bf16 bf16x8;
typedef __attribute__((ext_vector_type(16))) float f32x16;

__device__ __forceinline__ float sigmoid_fast(float x) {
    float e = __expf(-x);
    return __builtin_amdgcn_rcpf(1.0f + e);
}

__device__ __forceinline__ void gload16(const float* g, float* l) {
    __builtin_amdgcn_global_load_lds(
        (const __attribute__((address_space(1))) void*)g,
        (__attribute__((address_space(3))) void*)l, 16, 0, 0);
}

// Per-buffer LDS layout (6144 floats): array a at a*2048; row r at +r*64 (16 chunks of 16B).
// Staged so LDS[a][row][chunk c] = G_a[row][c ^ (row&15)] (XOR involution on the global side;
// verified correct in R6). Read of G[r][c] uses LDS chunk (c ^ (r&15)).
__global__ __launch_bounds__(256, 3) void cl_main(const float* __restrict__ in1,
                                                  const float* __restrict__ in2,
                                                  const float* __restrict__ msk,
                                                  float* __restrict__ ws) {
    __shared__ float smem[12288];   // 2 x 24KB buffers; reused for epilogue

    const int tid  = threadIdx.x;
    const int w    = tid >> 6;     // wave 0..3 = K-step owner
    const int lane = tid & 63;
    const int r    = lane & 31;    // MFMA fragment row this lane owns
    const int g    = lane >> 5;    // k-half within 16-col MFMA step
    const int jr   = lane >> 4;    // staging: row within group of 4 (0..3)
    const int jc   = lane & 15;    // staging: 16B chunk within 256B row-seg
    const int rsw  = r & 15;       // read-side swizzle key

    const float* arrs[3] = {in1, in2, msk};

    f32x16 acc;
    #pragma unroll
    for (int k = 0; k < 16; ++k) acc[k] = 0.0f;
    float pos = 0.0f, q1 = 0.0f, q2 = 0.0f;

    const int colbase = blockIdx.x * (TPB * BK);

    // ---- stage one tile: 24 x global_load_lds (1KB = 4 rows x 256B each), 6 per wave ----
    auto stage = [&](int p, int t) {
        const int coloff = colbase + t * BK;
        #pragma unroll
        for (int k = 0; k < 6; ++k) {
            const int n   = w * 6 + k;     // 0..23
            const int a   = n >> 3;        // array 0..2
            const int q   = n & 7;         // row group
            const int row = q * 4 + jr;    // per-lane row (0..31)
            gload16(arrs[a] + (size_t)row * NF + coloff + ((jc ^ (row & 15)) << 2),
                    smem + p * 6144 + a * 2048 + q * 256);
        }
    };

    // ---- compute current buffer: wave w owns K-step s = w (cols w*16 .. w*16+15) ----
    auto compute = [&](int p) {
        const int c1 = w * 4 + g * 2;      // logical 16B-chunk index
        const float* base = smem + p * 6144 + r * 64;
        float4 A0 = *(const float4*)(base +        ((c1       ^ rsw) << 2));
        float4 A1 = *(const float4*)(base +        (((c1 + 1) ^ rsw) << 2));
        float4 B0 = *(const float4*)(base + 2048 + ((c1       ^ rsw) << 2));
        float4 B1 = *(const float4*)(base + 2048 + (((c1 + 1) ^ rsw) << 2));
        float4 M0 = *(const float4*)(base + 4096 + ((c1       ^ rsw) << 2));
        float4 M1 = *(const float4*)(base + 4096 + (((c1 + 1) ^ rsw) << 2));

        float xa[8], xb[8], xm[8];
        *(float4*)&xa[0] = A0; *(float4*)&xa[4] = A1;
        *(float4*)&xb[0] = B0; *(float4*)&xb[4] = B1;
        *(float4*)&xm[0] = M0; *(float4*)&xm[4] = M1;

        bf16x8 fa, fb;
        #pragma unroll
        for (int e = 0; e < 8; ++e) {
            float sa = sigmoid_fast(xa[e]);
            float sb = sigmoid_fast(xb[e]);
            float d  = xm[e] * (sa - sb);
            pos = fmaf(d, d, pos);
            q1  = fmaf(sa, sa, q1);
            q2  = fmaf(sb, sb, q2);
            fa[e] = (__bf16)sa;
            fb[e] = (__bf16)sb;
        }
        acc = __builtin_amdgcn_mfma_f32_32x32x16_bf16(fa, fb, acc, 0, 0, 0);
    };

    // ---- T3 2-phase pipeline: issue next-tile loads BEFORE computing current ----
    stage(0, 0);
    __syncthreads();                       // drain prologue loads
    #pragma unroll
    for (int t = 0; t < TPB - 1; ++t) {
        stage((t + 1) & 1, t + 1);         // loads fly under compute
        compute(t & 1);
        __syncthreads();                   // single drain+sync per tile
    }
    compute((TPB - 1) & 1);                // last tile: no prefetch, no barrier yet

    // ---- atomic-free block epilogue: per-wave private LDS regions ----
    float* s_c = smem;                     // 4 x 1024 floats
    float* s_v = smem + 4096;              // 4 x 96 floats
    const int col = lane & 31;
    const int rhi = (lane >> 5) * 4;
    #pragma unroll
    for (int reg = 0; reg < 16; ++reg) {
        const int row = (reg & 3) + 8 * (reg >> 2) + rhi;  // verified C/D mapping
        s_c[w * 1024 + row * 32 + col] = acc[reg];         // each slot written once per wave
    }
    pos += __shfl_down(pos, 32);
    q1  += __shfl_down(q1, 32);
    q2  += __shfl_down(q2, 32);
    if (lane < 32) {
        s_v[w * 96 + r]      = pos;
        s_v[w * 96 + 32 + r] = q1;
        s_v[w * 96 + 64 + r] = q2;
    }
    __syncthreads();

    // ---- sharded global accumulation: one atomic per slot ----
    float* slice = ws + (size_t)(blockIdx.x & (NSLICES - 1)) * SLICE;
    for (int idx = tid; idx < 1024; idx += 256) {
        float s = s_c[idx] + s_c[1024 + idx] + s_c[2048 + idx] + s_c[3072 + idx];
        atomicAdd(&slice[idx], s);
    }
    if (tid < 96) {
        float s = s_v[tid] + s_v[96 + tid] + s_v[192 + tid] + s_v[288 + tid];
        atomicAdd(&slice[1024 + tid], s);
    }
}

__global__ __launch_bounds__(1024) void cl_final(const float* __restrict__ ws,
                                                 float* __restrict__ out) {
    __shared__ float s_loss[32];
    const int tid = threadIdx.x;
    const int i = tid >> 5, j = tid & 31;
    const float invN = 1.0f / (float)NF;

    float c = 0.0f, p = 0.0f, s1 = 0.0f, s2 = 0.0f;
    #pragma unroll
    for (int k = 0; k < NSLICES; ++k) {
        const float* sl = ws + (size_t)k * SLICE;
        c  += sl[i * 32 + j];
        p  += sl[1024 + i];
        s1 += sl[1056 + i];
        s2 += sl[1088 + j];
    }

    float d = (s1 + s2 - 2.0f * c) * invN;
    float sim = (i == j) ? 0.0f : expf(-d * 10.0f);   // TAU = 0.1
    #pragma unroll
    for (int off = 16; off; off >>= 1) sim += __shfl_xor(sim, off);

    if (j == 0) {
        float sp = expf(-p * invN * 10.0f);
        s_loss[i] = -logf(sp / (sp + sim));
    }
    __syncthreads();
    if (tid == 0) {
        float t = 0.0f;
        #pragma unroll
        for (int k = 0; k < 32; ++k) t += s_loss[k];
        out[0] = t * (1.0f / 32.0f);
    }
}

extern "C" void kernel_launch(void* const* d_in, const int* in_sizes, int n_in,
                              void* d_out, int out_size, void* d_ws, size_t ws_size,
                              hipStream_t stream) {
    const float* in1 = (const float*)d_in[0];
    const float* in2 = (const float*)d_in[1];
    const float* msk = (const float*)d_in[2];
    float* out = (float*)d_out;
    float* ws  = (float*)d_ws;

    hipMemsetAsync(ws, 0, NSLICES * SLICE * sizeof(float), stream);
    cl_main<<<1024, 256, 0, stream>>>(in1, in2, msk, ws);
    cl_final<<<1, 1024, 0, stream>>>(ws, out);
}

// Round 8
// 44.938 us; speedup vs baseline: 1.3342x; 1.0012x over previous
//
#include <hip/hip_runtime.h>
#include <hip/hip_bf16.h>

#define NF 262144    // C*H*W
#define NROWS 32     // batch
#define BK 64        // tile cols (floats) per stage
#define TPB 4        // tiles per block
#define NBLK 1024    // cl_main grid
#define PSTRIDE 1152 // floats per partial record: 1024 cross + 96 vec + pad
#define NKG 16       // reduce k-groups (cl_final reads 16 slices)

typedef __attribute__((ext_vector_type(8))) __bf16 bf16x8;
typedef __attribute__((ext_vector_type(16))) float f32x16;

__device__ __forceinline__ float sigmoid_fast(float x) {
    float e = __expf(-x);
    return __builtin_amdgcn_rcpf(1.0f + e);
}

__device__ __forceinline__ void gload16(const float* g, float* l) {
    __builtin_amdgcn_global_load_lds(
        (const __attribute__((address_space(1))) void*)g,
        (__attribute__((address_space(3))) void*)l, 16, 0, 0);
}

// Per-buffer LDS layout (6144 floats): array a at a*2048; row r at +r*64 (16 chunks of 16B).
// Staged so LDS[a][row][chunk c] = G_a[row][c ^ (row&15)] (XOR involution on the global side;
// verified correct in R6/R7). Read of G[r][c] uses LDS chunk (c ^ (r&15)).
__global__ __launch_bounds__(256, 3) void cl_main(const float* __restrict__ in1,
                                                  const float* __restrict__ in2,
                                                  const float* __restrict__ msk,
                                                  float* __restrict__ ws) {
    __shared__ float smem[12288];   // 2 x 24KB buffers; reused for epilogue

    const int tid  = threadIdx.x;
    const int w    = tid >> 6;     // wave 0..3 = K-step owner
    const int lane = tid & 63;
    const int r    = lane & 31;    // MFMA fragment row this lane owns
    const int g    = lane >> 5;    // k-half within 16-col MFMA step
    const int jr   = lane >> 4;    // staging: row within group of 4 (0..3)
    const int jc   = lane & 15;    // staging: 16B chunk within 256B row-seg
    const int rsw  = r & 15;       // read-side swizzle key

    const float* arrs[3] = {in1, in2, msk};

    f32x16 acc;
    #pragma unroll
    for (int k = 0; k < 16; ++k) acc[k] = 0.0f;
    float pos = 0.0f, q1 = 0.0f, q2 = 0.0f;

    const int colbase = blockIdx.x * (TPB * BK);

    auto stage = [&](int p, int t) {
        const int coloff = colbase + t * BK;
        #pragma unroll
        for (int k = 0; k < 6; ++k) {
            const int n   = w * 6 + k;     // 0..23
            const int a   = n >> 3;        // array 0..2
            const int q   = n & 7;         // row group
            const int row = q * 4 + jr;    // per-lane row (0..31)
            gload16(arrs[a] + (size_t)row * NF + coloff + ((jc ^ (row & 15)) << 2),
                    smem + p * 6144 + a * 2048 + q * 256);
        }
    };

    auto compute = [&](int p) {
        const int c1 = w * 4 + g * 2;      // logical 16B-chunk index (wave w owns K-step w)
        const float* base = smem + p * 6144 + r * 64;
        float4 A0 = *(const float4*)(base +        ((c1       ^ rsw) << 2));
        float4 A1 = *(const float4*)(base +        (((c1 + 1) ^ rsw) << 2));
        float4 B0 = *(const float4*)(base + 2048 + ((c1       ^ rsw) << 2));
        float4 B1 = *(const float4*)(base + 2048 + (((c1 + 1) ^ rsw) << 2));
        float4 M0 = *(const float4*)(base + 4096 + ((c1       ^ rsw) << 2));
        float4 M1 = *(const float4*)(base + 4096 + (((c1 + 1) ^ rsw) << 2));

        float xa[8], xb[8], xm[8];
        *(float4*)&xa[0] = A0; *(float4*)&xa[4] = A1;
        *(float4*)&xb[0] = B0; *(float4*)&xb[4] = B1;
        *(float4*)&xm[0] = M0; *(float4*)&xm[4] = M1;

        bf16x8 fa, fb;
        #pragma unroll
        for (int e = 0; e < 8; ++e) {
            float sa = sigmoid_fast(xa[e]);
            float sb = sigmoid_fast(xb[e]);
            float d  = xm[e] * (sa - sb);
            pos = fmaf(d, d, pos);
            q1  = fmaf(sa, sa, q1);
            q2  = fmaf(sb, sb, q2);
            fa[e] = (__bf16)sa;
            fb[e] = (__bf16)sb;
        }
        acc = __builtin_amdgcn_mfma_f32_32x32x16_bf16(fa, fb, acc, 0, 0, 0);
    };

    // ---- 2-phase pipeline: issue next-tile loads BEFORE computing current ----
    stage(0, 0);
    __syncthreads();
    #pragma unroll
    for (int t = 0; t < TPB - 1; ++t) {
        stage((t + 1) & 1, t + 1);
        compute(t & 1);
        __syncthreads();
    }
    compute((TPB - 1) & 1);   // last tile (buffer 1); epilogue regions below are in buffer 0 — no overlap

    // ---- atomic-free block epilogue: per-wave private LDS regions ----
    float* s_c = smem;                     // 4 x 1024 floats
    float* s_v = smem + 4096;              // 4 x 96 floats
    const int col = lane & 31;
    const int rhi = (lane >> 5) * 4;
    #pragma unroll
    for (int reg = 0; reg < 16; ++reg) {
        const int row = (reg & 3) + 8 * (reg >> 2) + rhi;  // verified C/D mapping
        s_c[w * 1024 + row * 32 + col] = acc[reg];
    }
    pos += __shfl_down(pos, 32);
    q1  += __shfl_down(q1, 32);
    q2  += __shfl_down(q2, 32);
    if (lane < 32) {
        s_v[w * 96 + r]      = pos;
        s_v[w * 96 + 32 + r] = q1;
        s_v[w * 96 + 64 + r] = q2;
    }
    __syncthreads();

    // ---- block-unique partial write: plain coalesced stores, NO atomics ----
    float* P = ws + (size_t)blockIdx.x * PSTRIDE;
    for (int idx = tid; idx < 1024; idx += 256) {
        P[idx] = s_c[idx] + s_c[1024 + idx] + s_c[2048 + idx] + s_c[3072 + idx];
    }
    if (tid < 96) {
        P[1024 + tid] = s_v[tid] + s_v[96 + tid] + s_v[192 + tid] + s_v[288 + tid];
    }
}

// Reduce 1024 partial records -> 16 slices of 1152.  Thread (kg, slot) sums 64
// records; lane-consecutive slots give fully coalesced loads.
__global__ __launch_bounds__(256) void cl_reduce(const float* __restrict__ ws,
                                                 float* __restrict__ out2) {
    const int kg   = blockIdx.x / 5;                 // 0..15
    const int sg   = blockIdx.x % 5;                 // 0..4
    const int slot = sg * 256 + threadIdx.x;         // 0..1279
    if (slot >= 1120) return;
    const float* base = ws + (size_t)kg * 64 * PSTRIDE + slot;
    float s = 0.0f;
    #pragma unroll 8
    for (int k = 0; k < 64; ++k) s += base[(size_t)k * PSTRIDE];
    out2[kg * PSTRIDE + slot] = s;
}

__global__ __launch_bounds__(1024) void cl_final(const float* __restrict__ ws2,
                                                 float* __restrict__ out) {
    __shared__ float s_loss[32];
    const int tid = threadIdx.x;
    const int i = tid >> 5, j = tid & 31;
    const float invN = 1.0f / (float)NF;

    float c = 0.0f, p = 0.0f, s1 = 0.0f, s2 = 0.0f;
    #pragma unroll
    for (int k = 0; k < NKG; ++k) {
        const float* sl = ws2 + (size_t)k * PSTRIDE;
        c  += sl[i * 32 + j];
        p  += sl[1024 + i];
        s1 += sl[1056 + i];
        s2 += sl[1088 + j];
    }

    float d = (s1 + s2 - 2.0f * c) * invN;
    float sim = (i == j) ? 0.0f : expf(-d * 10.0f);   // TAU = 0.1
    #pragma unroll
    for (int off = 16; off; off >>= 1) sim += __shfl_xor(sim, off);

    if (j == 0) {
        float sp = expf(-p * invN * 10.0f);
        s_loss[i] = -logf(sp / (sp + sim));
    }
    __syncthreads();
    if (tid == 0) {
        float t = 0.0f;
        #pragma unroll
        for (int k = 0; k < 32; ++k) t += s_loss[k];
        out[0] = t * (1.0f / 32.0f);
    }
}

extern "C" void kernel_launch(void* const* d_in, const int* in_sizes, int n_in,
                              void* d_out, int out_size, void* d_ws, size_t ws_size,
                              hipStream_t stream) {
    const float* in1 = (const float*)d_in[0];
    const float* in2 = (const float*)d_in[1];
    const float* msk = (const float*)d_in[2];
    float* out = (float*)d_out;
    float* ws  = (float*)d_ws;
    float* ws2 = ws + (size_t)NBLK * PSTRIDE;   // 16 x 1152 reduced slices

    cl_main  <<<NBLK, 256, 0, stream>>>(in1, in2, msk, ws);
    cl_reduce<<<80,   256, 0, stream>>>(ws, ws2);
    cl_final <<<1,   1024, 0, stream>>>(ws2, out);
}